// Round 13
// baseline (1112.637 us; speedup 1.0000x reference)
//
#include <hip/hip_runtime.h>

typedef unsigned short u16;
typedef __attribute__((ext_vector_type(8))) short bf16x8;
typedef __attribute__((ext_vector_type(4))) float f32x4;

__device__ __forceinline__ float bf2f(u16 u) {
  union { unsigned u; float f; } v; v.u = ((unsigned)u) << 16; return v.f;
}
__device__ __forceinline__ u16 f2bf(float f) {
  union { float f; unsigned u; } v; v.f = f;
  unsigned r = v.u + 0x7FFFu + ((v.u >> 16) & 1u);
  return (u16)(r >> 16);
}

// device-coherent (MALL) access helpers — bypass non-coherent per-XCD L2s
__device__ __forceinline__ f32x4 ld_sc_x4(const u16* p) {
  f32x4 r;
  asm volatile("global_load_dwordx4 %0, %1, off sc0 sc1"
               : "=v"(r) : "v"(p) : "memory");
  return r;
}
__device__ __forceinline__ float ld_sc_f32(const float* p) {
  float r;
  asm volatile("global_load_dword %0, %1, off sc0 sc1"
               : "=v"(r) : "v"(p) : "memory");
  return r;
}
__device__ __forceinline__ void st_sc_u16(u16* p, unsigned v) {
  asm volatile("global_store_short %0, %1, off sc0 sc1"
               :: "v"(p), "v"(v) : "memory");
}
__device__ __forceinline__ void st_sc_f32(float* p, float v) {
  asm volatile("global_store_dword %0, %1, off sc0 sc1"
               :: "v"(p), "v"(v) : "memory");
}
#define WAIT_VM0() asm volatile("s_waitcnt vmcnt(0)" ::: "memory")

__device__ __forceinline__ int ld_flag(const int* p) {
  return __hip_atomic_load(p, __ATOMIC_RELAXED, __HIP_MEMORY_SCOPE_AGENT);
}
__device__ __forceinline__ void st_flag(int* p, int v) {
  __hip_atomic_store(p, v, __ATOMIC_RELAXED, __HIP_MEMORY_SCOPE_AGENT);
}

// ---------------- scratch layout (bytes inside d_out scores region) ----------
constexpr size_t OFF_WCAT  = 0;             // bf16 [32000][1536]
constexpr size_t OFF_WSEM  = 98304000;      // bf16 [32000][1024] (dead after
constexpr size_t OFF_PART  = 98304000;      //   baseo GEMM; PART aliases it)
constexpr size_t OFF_H1ALL = 130000000;     // bf16 [128][16][1024]
constexpr size_t OFF_GI0   = 163840000;     // f32  [2048][3072]
constexpr size_t OFF_XOUT  = 189005824;     // bf16 [2048][1536]  (h1 | emb)
constexpr size_t OFF_H0ALL = 195297280;     // bf16 [128][16][1024]
constexpr size_t OFF_WIH0E = 199491584;     // bf16 [3072][512]
constexpr size_t OFF_WIH0S = 202637312;     // bf16 [3072][1024]  (syn slice)
constexpr size_t OFF_WHH0  = 208928768;     // bf16 [3072][1024]
constexpr size_t OFF_WIH1  = 215220224;     // bf16 [3072][1024]
constexpr size_t OFF_WHH1  = 221511680;     // bf16 [3072][1024]
constexpr size_t OFF_SYNB  = 227803136;     // bf16 [128][1024] (rows>=16 zero)
constexpr size_t OFF_SEMB  = 228065280;     // bf16 [128][1024]
constexpr size_t OFF_BASE0 = 228327424;     // f32  [128][3072]
constexpr size_t OFF_BASEO = 229900288;     // f32  [128][32000]
constexpr size_t OFF_H0IBF = 246284288;     // bf16 [16][1024]
constexpr size_t OFF_H1IBF = 246317056;     // bf16 [16][1024]
constexpr size_t OFF_FLAGS = 246349824;     // int [4096] flags (16 KB)
// real outputs
constexpr size_t OFF_HIDF  = 262144000;     // f32 [2][16][1024]
constexpr size_t OFF_LAST  = 262275072;     // f32 [16][1024]
constexpr size_t OFF_LOGIT = 262340608;     // f32 [2048][32000]

// ---------------- merged recurrence-weight convert (one kernel) --------------
__global__ __launch_bounds__(256) void conv_recw_k(
    const float* __restrict__ Wih0, const float* __restrict__ Whh0,
    const float* __restrict__ Wih1, const float* __restrict__ Whh1,
    u16* __restrict__ WIH0E, u16* __restrict__ WIH0S, u16* __restrict__ WHH0B,
    u16* __restrict__ WIH1B, u16* __restrict__ WHH1B) {
  int t = blockIdx.x * 256 + threadIdx.x;
  if (t >= 3072 * 576) return;
  int r = t / 576, c = t - r * 576;
  const float* s;
  u16* d;
  if (c < 64) {
    s = Wih0 + (size_t)r * 1536 + c * 8;
    d = WIH0E + (size_t)r * 512 + c * 8;
  } else if (c < 192) {
    s = Wih0 + (size_t)r * 1536 + 512 + (c - 64) * 8;
    d = WIH0S + (size_t)r * 1024 + (c - 64) * 8;
  } else if (c < 320) {
    s = Whh0 + (size_t)r * 1024 + (c - 192) * 8;
    d = WHH0B + (size_t)r * 1024 + (c - 192) * 8;
  } else if (c < 448) {
    s = Wih1 + (size_t)r * 1024 + (c - 320) * 8;
    d = WIH1B + (size_t)r * 1024 + (c - 320) * 8;
  } else {
    s = Whh1 + (size_t)r * 1024 + (c - 448) * 8;
    d = WHH1B + (size_t)r * 1024 + (c - 448) * 8;
  }
  float4 a = *(const float4*)s;
  float4 b = *(const float4*)(s + 4);
  bf16x8 o;
  o[0] = (short)f2bf(a.x); o[1] = (short)f2bf(a.y);
  o[2] = (short)f2bf(a.z); o[3] = (short)f2bf(a.w);
  o[4] = (short)f2bf(b.x); o[5] = (short)f2bf(b.y);
  o[6] = (short)f2bf(b.z); o[7] = (short)f2bf(b.w);
  *(bf16x8*)d = o;
}

// ---------------- merged Wout convert: one read -> WCAT + WSEM ---------------
__global__ __launch_bounds__(256) void conv_wout_k(
    const float* __restrict__ Wout, u16* __restrict__ WCAT,
    u16* __restrict__ WSEM) {
  int t = blockIdx.x * 256 + threadIdx.x;   // 32000 * 320 jobs
  int r = t / 320, c = (t - r * 320) * 8;
  const float* s = Wout + (size_t)r * 2560 + c;
  float4 a = *(const float4*)s;
  float4 b = *(const float4*)(s + 4);
  bf16x8 o;
  o[0] = (short)f2bf(a.x); o[1] = (short)f2bf(a.y);
  o[2] = (short)f2bf(a.z); o[3] = (short)f2bf(a.w);
  o[4] = (short)f2bf(b.x); o[5] = (short)f2bf(b.y);
  o[6] = (short)f2bf(b.z); o[7] = (short)f2bf(b.w);
  u16* dst;
  if (c < 1024)      dst = WCAT + (size_t)r * 1536 + c;
  else if (c < 2048) dst = WSEM + (size_t)r * 1024 + (c - 1024);
  else               dst = WCAT + (size_t)r * 1536 + 1024 + (c - 2048);
  *(bf16x8*)dst = o;
}

// ---------------- merged small init: pack syn, pack sem, init h + flags ------
__global__ __launch_bounds__(256) void small_init_k(
    const float* __restrict__ syn, const float* __restrict__ sem,
    const float* __restrict__ hidden, u16* __restrict__ SYNB,
    u16* __restrict__ SEMB, u16* __restrict__ h0b, u16* __restrict__ h1b,
    int* __restrict__ flags) {
  int bb = blockIdx.x;
  if (bb < 128) {
    const float* src = bb < 64 ? syn : sem;
    u16* dst = bb < 64 ? SYNB : SEMB;
    int t = (bb & 63) * 256 + threadIdx.x;   // 16384 jobs
    int row = t >> 7, c = (t & 127) * 8;
    bf16x8 o = {0, 0, 0, 0, 0, 0, 0, 0};
    if (row < 16) {
      const float* s = src + row * 1024 + c;
      float4 a = *(const float4*)s;
      float4 b = *(const float4*)(s + 4);
      o[0] = (short)f2bf(a.x); o[1] = (short)f2bf(a.y);
      o[2] = (short)f2bf(a.z); o[3] = (short)f2bf(a.w);
      o[4] = (short)f2bf(b.x); o[5] = (short)f2bf(b.y);
      o[6] = (short)f2bf(b.z); o[7] = (short)f2bf(b.w);
    }
    *(bf16x8*)(dst + (size_t)row * 1024 + c) = o;
  } else {
    int i = (bb - 128) * 256 + threadIdx.x;  // 16384
    h0b[i] = f2bf(hidden[i]);
    h1b[i] = f2bf(hidden[16384 + i]);
    if (i < 4096) flags[i] = 0;
  }
}

// ---------------- embedding gather -> bf16 into XOUT[:,1024:1536] ------------
__global__ __launch_bounds__(256) void gather_emb_k(
    const int* __restrict__ seq, const float* __restrict__ table,
    u16* __restrict__ xout) {
  int t0 = blockIdx.x * 256 + threadIdx.x;
  int tb = t0 >> 6, c = (t0 & 63) * 8;
  int tt = tb >> 4, b = tb & 15;
  int tok = seq[b * 128 + tt];
  const float* s = table + (size_t)tok * 512 + c;
  float4 a = *(const float4*)s;
  float4 bb = *(const float4*)(s + 4);
  bf16x8 o;
  o[0] = (short)f2bf(a.x);  o[1] = (short)f2bf(a.y);
  o[2] = (short)f2bf(a.z);  o[3] = (short)f2bf(a.w);
  o[4] = (short)f2bf(bb.x); o[5] = (short)f2bf(bb.y);
  o[6] = (short)f2bf(bb.z); o[7] = (short)f2bf(bb.w);
  *(bf16x8*)(xout + (size_t)tb * 1536 + 1024 + c) = o;
}

// ---------------- coalesced stage: [16][1024] bf16 -> swizzled LDS -----------
__device__ __forceinline__ void stage_tile(const u16* src, char* tile,
                                           int tid) {
  f32x4 tmp[8];
#pragma unroll
  for (int q = 0; q < 8; ++q) {
    int c = q * 256 + tid;
    int row = c >> 7, kc = c & 127;
    tmp[q] = ld_sc_x4(src + (size_t)row * 1024 + kc * 8);
  }
  WAIT_VM0();
  __builtin_amdgcn_sched_barrier(0);
#pragma unroll
  for (int q = 0; q < 8; ++q) {
    int c = q * 256 + tid;
    int row = c >> 7, kc = c & 127;
    int byte = (row * 2048 + kc * 16) ^ ((row & 7) << 4);
    *(bf16x8*)(tile + byte) = *(bf16x8*)&tmp[q];
  }
}

// ---------------- persistent 2-layer GRU (round-4 structure, ~494 us) --------
__global__ __launch_bounds__(256, 1) void gru_persist3_k(
    const float* __restrict__ hidden, const u16* __restrict__ h0i,
    const u16* __restrict__ h1i, const float* __restrict__ gi0,
    const u16* __restrict__ Whh0, const u16* __restrict__ Wih1,
    const u16* __restrict__ Whh1, const float* __restrict__ bhh0,
    const float* __restrict__ bih1, const float* __restrict__ bhh1,
    u16* __restrict__ h0all, u16* __restrict__ h1all, u16* __restrict__ xout,
    float* __restrict__ part, float* __restrict__ hidf,
    float* __restrict__ last, int* __restrict__ flags) {
  extern __shared__ char ldsb[];
  char* Ab = ldsb + 98304;
  float* Cl = (float*)(ldsb + 131072);
  const int tid = threadIdx.x, bid = blockIdx.x;
  const int wave = tid >> 6, lane = tid & 63;
  const int role = bid >> 6, lb = bid & 63, jb = lb * 16;
  int* f0 = flags, *fih = flags + 1024, *f1 = flags + 2048;

  // ---- stage weight slice into LDS (once) ----
  const u16* Wsrc = role == 0 ? Whh0 : (role == 1 ? Wih1 : Whh1);
  for (int idx = tid; idx < 48 * 128; idx += 256) {
    int row = idx >> 7, c = idx & 127;
    int g = row >> 4, jj2 = row & 15;
    const u16* src = Wsrc + (size_t)(g * 1024 + jb + jj2) * 1024 + c * 8;
    int byte = (row * 2048 + c * 16) ^ ((row & 7) << 4);
    *(bf16x8*)(ldsb + byte) = *(const bf16x8*)src;
  }

  // ---- per-thread epilogue identity: b = tid>>4, jj = tid&15 ----
  const int eb = tid >> 4, jj = tid & 15, j = jb + jj;
  float hp = 0.f, bR = 0.f, bZ = 0.f, bN = 0.f, iR = 0.f, iZ = 0.f, iN = 0.f;
  if (role == 0) {
    hp = hidden[eb * 1024 + j];
    bR = bhh0[j]; bZ = bhh0[1024 + j]; bN = bhh0[2048 + j];
  } else if (role == 2) {
    hp = hidden[16384 + eb * 1024 + j];
    bR = bhh1[j]; bZ = bhh1[1024 + j]; bN = bhh1[2048 + j];
    iR = bih1[j]; iZ = bih1[1024 + j]; iN = bih1[2048 + j];
  }
  __syncthreads();

  const int arow = lane & 15, aq = lane >> 4;
  for (int t = 0; t < 128; ++t) {
    // ---- 1. poll producer flags (lanes 0-63 of wave 0) ----
    if (role == 0) {
      if (t > 0 && tid < 64)
        while (ld_flag(f0 + tid * 16) < t) __builtin_amdgcn_s_sleep(1);
    } else if (role == 1) {
      if (tid < 64)
        while (ld_flag(f0 + tid * 16) < t + 1) __builtin_amdgcn_s_sleep(1);
    } else {
      if (t > 0 && tid < 64)
        while (ld_flag(f1 + tid * 16) < t) __builtin_amdgcn_s_sleep(1);
    }
    __syncthreads();

    // ---- 2. stage A tile (device-coherent loads -> swizzled LDS) ----
    const u16* asrc;
    if (role == 0)      asrc = t ? h0all + (size_t)(t - 1) * 16384 : h0i;
    else if (role == 1) asrc = h0all + (size_t)t * 16384;
    else                asrc = t ? h1all + (size_t)(t - 1) * 16384 : h1i;
    stage_tile(asrc, Ab, tid);
    __syncthreads();

    // ---- 3. MFMA: 3 gate chains (ILP), A+B from LDS; wave w does ks=w+4i ----
    {
      f32x4 a0 = {0.f, 0.f, 0.f, 0.f}, a1 = a0, a2 = a0;
#pragma unroll
      for (int i = 0; i < 8; ++i) {
        int ks = wave + i * 4;
        int abyte = (arow * 2048 + ks * 64 + aq * 16) ^ ((arow & 7) << 4);
        bf16x8 af = *(const bf16x8*)(Ab + abyte);
        int r0 = arow, r1 = 16 + arow, r2 = 32 + arow;
        bf16x8 b0 = *(const bf16x8*)(
            ldsb + ((r0 * 2048 + ks * 64 + aq * 16) ^ ((r0 & 7) << 4)));
        bf16x8 b1 = *(const bf16x8*)(
            ldsb + ((r1 * 2048 + ks * 64 + aq * 16) ^ ((r1 & 7) << 4)));
        bf16x8 b2 = *(const bf16x8*)(
            ldsb + ((r2 * 2048 + ks * 64 + aq * 16) ^ ((r2 & 7) << 4)));
        a0 = __builtin_amdgcn_mfma_f32_16x16x32_bf16(af, b0, a0, 0, 0, 0);
        a1 = __builtin_amdgcn_mfma_f32_16x16x32_bf16(af, b1, a1, 0, 0, 0);
        a2 = __builtin_amdgcn_mfma_f32_16x16x32_bf16(af, b2, a2, 0, 0, 0);
      }
#pragma unroll
      for (int r = 0; r < 4; ++r) {
        int ci = (aq * 4 + r) * 16 + arow + aq * 8;  // conflict-break offset
        Cl[(0 * 4 + wave) * 288 + ci] = a0[r];
        Cl[(1 * 4 + wave) * 288 + ci] = a1[r];
        Cl[(2 * 4 + wave) * 288 + ci] = a2[r];
      }
    }
    // hh: wait for this stage's gi1 partial flag while C settles
    if (role == 2 && tid == 0)
      while (ld_flag(fih + lb * 16) < t + 1) __builtin_amdgcn_s_sleep(1);
    __syncthreads();

    // ---- 4. epilogue ----
    {
      int ci = eb * 16 + jj + (eb >> 2) * 8;
      float s0 = Cl[0 * 288 + ci] + Cl[1 * 288 + ci] +
                 Cl[2 * 288 + ci] + Cl[3 * 288 + ci];
      float s1 = Cl[4 * 288 + ci] + Cl[5 * 288 + ci] +
                 Cl[6 * 288 + ci] + Cl[7 * 288 + ci];
      float s2 = Cl[8 * 288 + ci] + Cl[9 * 288 + ci] +
                 Cl[10 * 288 + ci] + Cl[11 * 288 + ci];
      if (role == 1) {
        float* pp = part + ((size_t)t * 64 + lb) * 768 + eb * 16 + jj;
        st_sc_f32(pp, s0);
        st_sc_f32(pp + 256, s1);
        st_sc_f32(pp + 512, s2);
        WAIT_VM0();
      } else {
        float ir, iz, inn;
        if (role == 0) {
          const float* g = gi0 + ((size_t)t * 16 + eb) * 3072 + j;
          ir = g[0]; iz = g[1024]; inn = g[2048];
        } else {
          const float* pp = part + ((size_t)t * 64 + lb) * 768 + eb * 16 + jj;
          float p0 = ld_sc_f32(pp), p1 = ld_sc_f32(pp + 256),
                p2 = ld_sc_f32(pp + 512);
          WAIT_VM0();
          __builtin_amdgcn_sched_barrier(0);  // rule #18: pin VALU below wait
          ir = p0 + iR; iz = p1 + iZ; inn = p2 + iN;
        }
        float r = 1.f / (1.f + __expf(-(ir + s0 + bR)));
        float z = 1.f / (1.f + __expf(-(iz + s1 + bZ)));
        float n = tanhf(inn + r * (s2 + bN));
        float hnew = (1.f - z) * n + z * hp;
        hp = hnew;
        u16 hb = f2bf(hnew);
        if (role == 0) {
          st_sc_u16(h0all + ((size_t)t * 16 + eb) * 1024 + j, (unsigned)hb);
          if (t == 127) hidf[eb * 1024 + j] = hnew;
        } else {
          st_sc_u16(h1all + ((size_t)t * 16 + eb) * 1024 + j, (unsigned)hb);
          xout[((size_t)t * 16 + eb) * 1536 + j] = hb;  // plain store
          if (t == 127) {
            hidf[16384 + eb * 1024 + j] = hnew;
            last[eb * 1024 + j] = hnew;
          }
        }
        WAIT_VM0();
      }
    }
    __syncthreads();
    // ---- 5. publish flag ----
    if (tid == 0) {
      if (role == 0)      st_flag(f0 + lb * 16, t + 1);
      else if (role == 1) st_flag(fih + lb * 16, t + 1);
      else                st_flag(f1 + lb * 16, t + 1);
    }
  }
}

// ---------------- bf16 MFMA GEMM (BM=128, 3-buffer counted-vmcnt) ------------
template <int MODE>
__global__ __launch_bounds__(256) void gemm_bt_k(
    const u16* __restrict__ A, int lda, const u16* __restrict__ Bw, int ldb,
    float* __restrict__ C, int ldc, const float* __restrict__ add,
    int N, int K) {
  __shared__ u16 Asm_[3][128 * 32];
  __shared__ u16 Bsm_[3][128 * 32];
  const int m0 = blockIdx.x * 128, n0 = blockIdx.y * 128;
  const int tid = threadIdx.x, wave = tid >> 6, lane = tid & 63;
  const int wm = (wave >> 1) * 64, wn = (wave & 1) * 64;
  const int lrow = lane & 15, lk = (lane >> 4) * 8;

  auto STAGE = [&](int buf, int k0) {
#pragma unroll
    for (int q = 0; q < 2; ++q) {
      int c = (wave * 2 + q) * 64 + lane;
      int row = c >> 2, seg = c & 3;
      const u16* src = A + (size_t)(m0 + row) * lda + k0 + seg * 8;
      u16* dst = Asm_[buf] + (wave * 2 + q) * 512;
      __builtin_amdgcn_global_load_lds(
          (const __attribute__((address_space(1))) void*)src,
          (__attribute__((address_space(3))) void*)dst, 16, 0, 0);
    }
#pragma unroll
    for (int q = 0; q < 2; ++q) {
      int c = (wave * 2 + q) * 64 + lane;
      int row = c >> 2, seg = c & 3;
      const u16* src = Bw + (size_t)(n0 + row) * ldb + k0 + seg * 8;
      u16* dst = Bsm_[buf] + (wave * 2 + q) * 512;
      __builtin_amdgcn_global_load_lds(
          (const __attribute__((address_space(1))) void*)src,
          (__attribute__((address_space(3))) void*)dst, 16, 0, 0);
    }
  };

  const int nIt = K >> 5;
  STAGE(0, 0);
  if (1 < nIt) STAGE(1, 32);
  f32x4 acc[4][4] = {};
  for (int it = 0; it < nIt; ++it) {
    const int cur = it % 3;
    if (it + 1 < nIt) { asm volatile("s_waitcnt vmcnt(4)" ::: "memory"); }
    else              { asm volatile("s_waitcnt vmcnt(0)" ::: "memory"); }
    __syncthreads();
    if (it + 2 < nIt) STAGE((it + 2) % 3, (it + 2) * 32);
    bf16x8 af[4], bfr[4];
#pragma unroll
    for (int i = 0; i < 4; ++i) {
      af[i]  = *(const bf16x8*)(Asm_[cur] + (wm + i * 16 + lrow) * 32 + lk);
      bfr[i] = *(const bf16x8*)(Bsm_[cur] + (wn + i * 16 + lrow) * 32 + lk);
    }
#pragma unroll
    for (int i = 0; i < 4; ++i)
#pragma unroll
      for (int jx = 0; jx < 4; ++jx)
        acc[i][jx] = __builtin_amdgcn_mfma_f32_16x16x32_bf16(
            af[i], bfr[jx], acc[i][jx], 0, 0, 0);
  }
  const int lr4 = (lane >> 4) * 4;
#pragma unroll
  for (int i = 0; i < 4; ++i) {
#pragma unroll
    for (int jx = 0; jx < 4; ++jx) {
      int gc = n0 + wn + jx * 16 + lrow;
#pragma unroll
      for (int r = 0; r < 4; ++r) {
        int gr = m0 + wm + i * 16 + lr4 + r;
        float v = acc[i][jx][r];
        if (MODE == 1) v += add[(gr & 15) * N + gc];
        else if (MODE == 2) v += add[gc];
        C[(size_t)gr * ldc + gc] = v;
      }
    }
  }
}

// ---------------- bf16 MFMA GEMM (BM=256, BN=128, 512 thr, 3-buffer) ---------
// Used for gi0 (N=3072). LDS 72 KB dynamic, 2 blocks/CU.
template <int MODE, bool SWZ>
__global__ __launch_bounds__(512) void gemm256_bt_k(
    const u16* __restrict__ A, int lda, const u16* __restrict__ Bw, int ldb,
    float* __restrict__ C, int ldc, const float* __restrict__ add,
    int N, int K) {
  extern __shared__ u16 lds256[];
  u16* Asm_ = lds256;              // 3 x 8192 u16 (16 KB each)
  u16* Bsm_ = lds256 + 3 * 8192;   // 3 x 4096 u16 (8 KB each)
  int bx = blockIdx.x, by = blockIdx.y;
  if (SWZ) {
    int nx = gridDim.x;
    int orig = by * nx + bx;
    int cpx = (nx * gridDim.y) >> 3;
    int wg = (orig & 7) * cpx + (orig >> 3);
    bx = wg % nx; by = wg / nx;
  }
  const int m0 = bx * 256, n0 = by * 128;
  const int tid = threadIdx.x, wave = tid >> 6, lane = tid & 63;
  const int wm = (wave >> 1) * 64, wn = (wave & 1) * 64;
  const int lrow = lane & 15, lk = (lane >> 4) * 8;

  auto STAGE = [&](int buf, int k0) {
#pragma unroll
    for (int q = 0; q < 2; ++q) {                    // A: 256x32 = 16KB
      int c = (q * 8 + wave) * 64 + lane;
      int row = c >> 2, seg = c & 3;
      const u16* src = A + (size_t)(m0 + row) * lda + k0 + seg * 8;
      u16* dst = Asm_ + buf * 8192 + (q * 8 + wave) * 512;
      __builtin_amdgcn_global_load_lds(
          (const __attribute__((address_space(1))) void*)src,
          (__attribute__((address_space(3))) void*)dst, 16, 0, 0);
    }
    {                                                // B: 128x32 = 8KB
      int c = wave * 64 + lane;
      int row = c >> 2, seg = c & 3;
      const u16* src = Bw + (size_t)(n0 + row) * ldb + k0 + seg * 8;
      u16* dst = Bsm_ + buf * 4096 + wave * 512;
      __builtin_amdgcn_global_load_lds(
          (const __attribute__((address_space(1))) void*)src,
          (__attribute__((address_space(3))) void*)dst, 16, 0, 0);
    }
  };

  const int nIt = K >> 5;
  STAGE(0, 0);
  if (1 < nIt) STAGE(1, 32);
  f32x4 acc[4][4] = {};
  for (int it = 0; it < nIt; ++it) {
    const int cur = it % 3;
    if (it + 1 < nIt) { asm volatile("s_waitcnt vmcnt(3)" ::: "memory"); }
    else              { asm volatile("s_waitcnt vmcnt(0)" ::: "memory"); }
    __syncthreads();
    if (it + 2 < nIt) STAGE((it + 2) % 3, (it + 2) * 32);
    bf16x8 af[4], bfr[4];
#pragma unroll
    for (int i = 0; i < 4; ++i) {
      af[i]  = *(const bf16x8*)(Asm_ + cur * 8192 + (wm + i * 16 + lrow) * 32 + lk);
      bfr[i] = *(const bf16x8*)(Bsm_ + cur * 4096 + (wn + i * 16 + lrow) * 32 + lk);
    }
#pragma unroll
    for (int i = 0; i < 4; ++i)
#pragma unroll
      for (int jx = 0; jx < 4; ++jx)
        acc[i][jx] = __builtin_amdgcn_mfma_f32_16x16x32_bf16(
            af[i], bfr[jx], acc[i][jx], 0, 0, 0);
  }
  const int lr4 = (lane >> 4) * 4;
#pragma unroll
  for (int i = 0; i < 4; ++i) {
#pragma unroll
    for (int jx = 0; jx < 4; ++jx) {
      int gc = n0 + wn + jx * 16 + lrow;
#pragma unroll
      for (int r = 0; r < 4; ++r) {
        int gr = m0 + wm + i * 16 + lr4 + r;
        float v = acc[i][jx][r];
        if (MODE == 1) v += add[(gr & 15) * N + gc];
        else if (MODE == 2) v += add[gc];
        C[(size_t)gr * ldc + gc] = v;
      }
    }
  }
}

// ---------------- bf16 MFMA GEMM (256x256 tile, 8 waves 2x4, 3-buffer) -------
// Per wave: C = 128x64 (acc[8][4]); 32 MFMA per BK=32 step — 2x compute
// density per barrier vs BN=128. LDS 3 x 32 KB = 96 KB, 1 block/CU.
template <int MODE, bool SWZ>
__global__ __launch_bounds__(512, 1) void gemm256x256_bt_k(
    const u16* __restrict__ A, int lda, const u16* __restrict__ Bw, int ldb,
    float* __restrict__ C, int ldc, const float* __restrict__ add,
    int N, int K) {
  extern __shared__ u16 ldsq[];
  u16* Asm_ = ldsq;                // 3 x 8192 u16 (16 KB each)
  u16* Bsm_ = ldsq + 3 * 8192;     // 3 x 8192 u16 (16 KB each)
  int bx = blockIdx.x, by = blockIdx.y;
  if (SWZ) {
    int nx = gridDim.x;
    int orig = by * nx + bx;
    int cpx = (nx * gridDim.y) >> 3;   // grid size must be divisible by 8
    int wg = (orig & 7) * cpx + (orig >> 3);
    bx = wg % nx; by = wg / nx;
  }
  const int m0 = bx * 256, n0 = by * 256;
  const int tid = threadIdx.x, wave = tid >> 6, lane = tid & 63;
  const int wm = (wave >> 2) * 128, wn = (wave & 3) * 64;   // 2x4 wave grid
  const int lrow = lane & 15, lk = (lane >> 4) * 8;

  auto STAGE = [&](int buf, int k0) {
#pragma unroll
    for (int q = 0; q < 2; ++q) {                    // A: 256x32 = 16KB
      int c = (q * 8 + wave) * 64 + lane;
      int row = c >> 2, seg = c & 3;
      const u16* src = A + (size_t)(m0 + row) * lda + k0 + seg * 8;
      u16* dst = Asm_ + buf * 8192 + (q * 8 + wave) * 512;
      __builtin_amdgcn_global_load_lds(
          (const __attribute__((address_space(1))) void*)src,
          (__attribute__((address_space(3))) void*)dst, 16, 0, 0);
    }
#pragma unroll
    for (int q = 0; q < 2; ++q) {                    // B: 256x32 = 16KB
      int c = (q * 8 + wave) * 64 + lane;
      int row = c >> 2, seg = c & 3;
      const u16* src = Bw + (size_t)(n0 + row) * ldb + k0 + seg * 8;
      u16* dst = Bsm_ + buf * 8192 + (q * 8 + wave) * 512;
      __builtin_amdgcn_global_load_lds(
          (const __attribute__((address_space(1))) void*)src,
          (__attribute__((address_space(3))) void*)dst, 16, 0, 0);
    }
  };

  const int nIt = K >> 5;
  STAGE(0, 0);
  if (1 < nIt) STAGE(1, 32);
  f32x4 acc[8][4] = {};
  for (int it = 0; it < nIt; ++it) {
    const int cur = it % 3;
    // retire STAGE(it)'s 4 loads; STAGE(it+1)'s 4 stay in flight
    if (it + 1 < nIt) { asm volatile("s_waitcnt vmcnt(4)" ::: "memory"); }
    else              { asm volatile("s_waitcnt vmcnt(0)" ::: "memory"); }
    __syncthreads();
    if (it + 2 < nIt) STAGE((it + 2) % 3, (it + 2) * 32);
    bf16x8 af[8], bfr[4];
#pragma unroll
    for (int i = 0; i < 8; ++i)
      af[i] = *(const bf16x8*)(Asm_ + cur * 8192 + (wm + i * 16 + lrow) * 32 + lk);
#pragma unroll
    for (int jx = 0; jx < 4; ++jx)
      bfr[jx] = *(const bf16x8*)(Bsm_ + cur * 8192 + (wn + jx * 16 + lrow) * 32 + lk);
#pragma unroll
    for (int i = 0; i < 8; ++i)
#pragma unroll
      for (int jx = 0; jx < 4; ++jx)
        acc[i][jx] = __builtin_amdgcn_mfma_f32_16x16x32_bf16(
            af[i], bfr[jx], acc[i][jx], 0, 0, 0);
  }
  const int lr4 = (lane >> 4) * 4;
#pragma unroll
  for (int i = 0; i < 8; ++i) {
#pragma unroll
    for (int jx = 0; jx < 4; ++jx) {
      int gc = n0 + wn + jx * 16 + lrow;
#pragma unroll
      for (int r = 0; r < 4; ++r) {
        int gr = m0 + wm + i * 16 + lr4 + r;
        float v = acc[i][jx][r];
        if (MODE == 1) v += add[(gr & 15) * N + gc];
        else if (MODE == 2) v += add[gc];
        C[(size_t)gr * ldc + gc] = v;
      }
    }
  }
}

// ---------------- row-wise log_softmax, online (m,s) single read pass --------
__global__ __launch_bounds__(256) void log_softmax_k(
    const float* __restrict__ logits, float* __restrict__ scores) {
  int row = blockIdx.x;
  const float* x = logits + (size_t)row * 32000;
  float* y = scores + (size_t)row * 32000;
  __shared__ float redm[4], reds[4];
  int tid = threadIdx.x;
  float m = -3.4e38f, s = 0.f;
  for (int idx = tid * 4; idx < 32000; idx += 1024) {
    float4 v = *(const float4*)(x + idx);
    float cm = fmaxf(fmaxf(v.x, v.y), fmaxf(v.z, v.w));
    if (cm > m) { s *= __expf(m - cm); m = cm; }
    s += __expf(v.x - m) + __expf(v.y - m) + __expf(v.z - m) + __expf(v.w - m);
  }
  for (int off = 1; off < 64; off <<= 1) {
    float mo = __shfl_xor(m, off), so = __shfl_xor(s, off);
    float nm = fmaxf(m, mo);
    s = s * __expf(m - nm) + so * __expf(mo - nm);
    m = nm;
  }
  if ((tid & 63) == 0) { redm[tid >> 6] = m; reds[tid >> 6] = s; }
  __syncthreads();
  {
    float fm = fmaxf(fmaxf(redm[0], redm[1]), fmaxf(redm[2], redm[3]));
    float fs = reds[0] * __expf(redm[0] - fm) + reds[1] * __expf(redm[1] - fm) +
               reds[2] * __expf(redm[2] - fm) + reds[3] * __expf(redm[3] - fm);
    float lse = fm + logf(fs);
    for (int idx = tid * 4; idx < 32000; idx += 1024) {
      float4 v = *(const float4*)(x + idx);
      float4 o;
      o.x = v.x - lse; o.y = v.y - lse; o.z = v.z - lse; o.w = v.w - lse;
      *(float4*)(y + idx) = o;
    }
  }
}

// =============================================================================
extern "C" void kernel_launch(void* const* d_in, const int* in_sizes, int n_in,
                              void* d_out, int out_size, void* d_ws,
                              size_t ws_size, hipStream_t stream) {
  const int*   seq    = (const int*)d_in[0];
  const float* sem    = (const float*)d_in[2];
  const float* syn    = (const float*)d_in[3];
  const float* hidden = (const float*)d_in[4];
  const float* table  = (const float*)d_in[5];
  const float* Wih0   = (const float*)d_in[6];
  const float* Whh0   = (const float*)d_in[7];
  const float* bih0   = (const float*)d_in[8];
  const float* bhh0   = (const float*)d_in[9];
  const float* Wih1   = (const float*)d_in[10];
  const float* Whh1   = (const float*)d_in[11];
  const float* bih1   = (const float*)d_in[12];
  const float* bhh1   = (const float*)d_in[13];
  const float* Wout   = (const float*)d_in[14];
  const float* bout   = (const float*)d_in[15];

  char* base = (char*)d_out;
  float* scores = (float*)base;
  u16*   WCAT   = (u16*)(base + OFF_WCAT);
  u16*   WSEM   = (u16*)(base + OFF_WSEM);
  float* PART   = (float*)(base + OFF_PART);
  u16*   H1ALL  = (u16*)(base + OFF_H1ALL);
  float* GI0    = (float*)(base + OFF_GI0);
  u16*   XOUT   = (u16*)(base + OFF_XOUT);
  u16*   H0ALL  = (u16*)(base + OFF_H0ALL);
  u16*   WIH0E  = (u16*)(base + OFF_WIH0E);
  u16*   WIH0S  = (u16*)(base + OFF_WIH0S);
  u16*   WHH0B  = (u16*)(base + OFF_WHH0);
  u16*   WIH1B  = (u16*)(base + OFF_WIH1);
  u16*   WHH1B  = (u16*)(base + OFF_WHH1);
  u16*   SYNB   = (u16*)(base + OFF_SYNB);
  u16*   SEMB   = (u16*)(base + OFF_SEMB);
  float* BASE0  = (float*)(base + OFF_BASE0);
  float* BASEO  = (float*)(base + OFF_BASEO);
  u16*   H0IBF  = (u16*)(base + OFF_H0IBF);
  u16*   H1IBF  = (u16*)(base + OFF_H1IBF);
  int*   FLAGS  = (int*)(base + OFF_FLAGS);
  float* hidf   = (float*)(base + OFF_HIDF);
  float* last   = (float*)(base + OFF_LAST);
  float* logits = (float*)(base + OFF_LOGIT);

  // weight conversions to bf16 (merged: Wout one pass; recurrence one kernel)
  conv_wout_k<<<40000, 256, 0, stream>>>(Wout, WCAT, WSEM);
  conv_recw_k<<<6912, 256, 0, stream>>>(
      Wih0, Whh0, Wih1, Whh1, WIH0E, WIH0S, WHH0B, WIH1B, WHH1B);

  // embeddings + packed small operands + init (merged)
  gather_emb_k<<<512, 256, 0, stream>>>(seq, table, XOUT);
  small_init_k<<<192, 256, 0, stream>>>(
      syn, sem, hidden, SYNB, SEMB, H0IBF, H1IBF, FLAGS);

  // time-invariant bases via MFMA GEMM (M padded to 128; rows 16..127 junk)
  gemm_bt_k<2><<<dim3(1, 24), 256, 0, stream>>>(
      SYNB, 1024, WIH0S, 1024, BASE0, 3072, bih0, 3072, 1024);
  gemm_bt_k<2><<<dim3(1, 250), 256, 0, stream>>>(
      SEMB, 1024, WSEM, 1024, BASEO, 32000, bout, 32000, 1024);

  // gi0 for all t: embs @ Wih0e.T + base0 (BM=256xBN=128, grid 192 = 8*24)
  hipFuncSetAttribute((const void*)(gemm256_bt_k<1, true>),
                      hipFuncAttributeMaxDynamicSharedMemorySize, 73728);
  gemm256_bt_k<1, true><<<dim3(8, 24), 512, 73728, stream>>>(
      XOUT + 1024, 1536, WIH0E, 512, GI0, 3072, BASE0, 3072, 512);

  // persistent recurrence (round-4 structure; PART overwrites dead WSEM)
  hipFuncSetAttribute((const void*)gru_persist3_k,
                      hipFuncAttributeMaxDynamicSharedMemorySize, 145408);
  gru_persist3_k<<<192, 256, 145408, stream>>>(
      hidden, H0IBF, H1IBF, GI0, WHH0B, WIH1B, WHH1B, bhh0, bih1, bhh1,
      H0ALL, H1ALL, XOUT, PART, hidf, last, FLAGS);

  // logits = [h1 | emb] @ WCAT.T + baseo (256x256 tile, grid 1000 = 8*125)
  hipFuncSetAttribute((const void*)(gemm256x256_bt_k<1, true>),
                      hipFuncAttributeMaxDynamicSharedMemorySize, 98304);
  gemm256x256_bt_k<1, true><<<dim3(8, 125), 512, 98304, stream>>>(
      XOUT, 1536, WCAT, 1536, logits, 32000, BASEO, 32000, 1536);

  // scores = log_softmax(logits) — the only writer of the scores region
  log_softmax_k<<<2048, 256, 0, stream>>>(logits, scores);
}

// Round 14
// 1068.022 us; speedup vs baseline: 1.0418x; 1.0418x over previous
//
#include <hip/hip_runtime.h>

typedef unsigned short u16;
typedef __attribute__((ext_vector_type(8))) short bf16x8;
typedef __attribute__((ext_vector_type(4))) float f32x4;

__device__ __forceinline__ float bf2f(u16 u) {
  union { unsigned u; float f; } v; v.u = ((unsigned)u) << 16; return v.f;
}
__device__ __forceinline__ u16 f2bf(float f) {
  union { float f; unsigned u; } v; v.f = f;
  unsigned r = v.u + 0x7FFFu + ((v.u >> 16) & 1u);
  return (u16)(r >> 16);
}

// device-coherent (MALL) access helpers — bypass non-coherent per-XCD L2s
__device__ __forceinline__ f32x4 ld_sc_x4(const u16* p) {
  f32x4 r;
  asm volatile("global_load_dwordx4 %0, %1, off sc0 sc1"
               : "=v"(r) : "v"(p) : "memory");
  return r;
}
__device__ __forceinline__ float ld_sc_f32(const float* p) {
  float r;
  asm volatile("global_load_dword %0, %1, off sc0 sc1"
               : "=v"(r) : "v"(p) : "memory");
  return r;
}
__device__ __forceinline__ void st_sc_u16(u16* p, unsigned v) {
  asm volatile("global_store_short %0, %1, off sc0 sc1"
               :: "v"(p), "v"(v) : "memory");
}
__device__ __forceinline__ void st_sc_f32(float* p, float v) {
  asm volatile("global_store_dword %0, %1, off sc0 sc1"
               :: "v"(p), "v"(v) : "memory");
}
#define WAIT_VM0() asm volatile("s_waitcnt vmcnt(0)" ::: "memory")

__device__ __forceinline__ int ld_flag(const int* p) {
  return __hip_atomic_load(p, __ATOMIC_RELAXED, __HIP_MEMORY_SCOPE_AGENT);
}
__device__ __forceinline__ void st_flag(int* p, int v) {
  __hip_atomic_store(p, v, __ATOMIC_RELAXED, __HIP_MEMORY_SCOPE_AGENT);
}

// ---------------- scratch layout (bytes inside d_out scores region) ----------
constexpr size_t OFF_WCAT  = 0;             // bf16 [32000][1536]
constexpr size_t OFF_WSEM  = 98304000;      // bf16 [32000][1024] (dead after
constexpr size_t OFF_PART  = 98304000;      //   baseo GEMM; PART aliases it)
constexpr size_t OFF_H1ALL = 130000000;     // bf16 [128][16][1024]
constexpr size_t OFF_GI0   = 163840000;     // f32  [2048][3072]
constexpr size_t OFF_XOUT  = 189005824;     // bf16 [2048][1536]  (h1 | emb)
constexpr size_t OFF_H0ALL = 195297280;     // bf16 [128][16][1024]
constexpr size_t OFF_WIH0E = 199491584;     // bf16 [3072][512]
constexpr size_t OFF_WIH0S = 202637312;     // bf16 [3072][1024]  (syn slice)
constexpr size_t OFF_WHH0  = 208928768;     // bf16 [3072][1024]
constexpr size_t OFF_WIH1  = 215220224;     // bf16 [3072][1024]
constexpr size_t OFF_WHH1  = 221511680;     // bf16 [3072][1024]
constexpr size_t OFF_SYNB  = 227803136;     // bf16 [128][1024] (rows>=16 zero)
constexpr size_t OFF_SEMB  = 228065280;     // bf16 [128][1024]
constexpr size_t OFF_BASE0 = 228327424;     // f32  [128][3072]
constexpr size_t OFF_BASEO = 229900288;     // f32  [128][32000]
constexpr size_t OFF_H0IBF = 246284288;     // bf16 [16][1024]
constexpr size_t OFF_H1IBF = 246317056;     // bf16 [16][1024]
constexpr size_t OFF_FLAGS = 246349824;     // int [4096] flags (16 KB)
// real outputs
constexpr size_t OFF_HIDF  = 262144000;     // f32 [2][16][1024]
constexpr size_t OFF_LAST  = 262275072;     // f32 [16][1024]
constexpr size_t OFF_LOGIT = 262340608;     // f32 [2048][32000]

// ---------------- merged recurrence-weight convert (one kernel) --------------
__global__ __launch_bounds__(256) void conv_recw_k(
    const float* __restrict__ Wih0, const float* __restrict__ Whh0,
    const float* __restrict__ Wih1, const float* __restrict__ Whh1,
    u16* __restrict__ WIH0E, u16* __restrict__ WIH0S, u16* __restrict__ WHH0B,
    u16* __restrict__ WIH1B, u16* __restrict__ WHH1B) {
  int t = blockIdx.x * 256 + threadIdx.x;
  if (t >= 3072 * 576) return;
  int r = t / 576, c = t - r * 576;
  const float* s;
  u16* d;
  if (c < 64) {
    s = Wih0 + (size_t)r * 1536 + c * 8;
    d = WIH0E + (size_t)r * 512 + c * 8;
  } else if (c < 192) {
    s = Wih0 + (size_t)r * 1536 + 512 + (c - 64) * 8;
    d = WIH0S + (size_t)r * 1024 + (c - 64) * 8;
  } else if (c < 320) {
    s = Whh0 + (size_t)r * 1024 + (c - 192) * 8;
    d = WHH0B + (size_t)r * 1024 + (c - 192) * 8;
  } else if (c < 448) {
    s = Wih1 + (size_t)r * 1024 + (c - 320) * 8;
    d = WIH1B + (size_t)r * 1024 + (c - 320) * 8;
  } else {
    s = Whh1 + (size_t)r * 1024 + (c - 448) * 8;
    d = WHH1B + (size_t)r * 1024 + (c - 448) * 8;
  }
  float4 a = *(const float4*)s;
  float4 b = *(const float4*)(s + 4);
  bf16x8 o;
  o[0] = (short)f2bf(a.x); o[1] = (short)f2bf(a.y);
  o[2] = (short)f2bf(a.z); o[3] = (short)f2bf(a.w);
  o[4] = (short)f2bf(b.x); o[5] = (short)f2bf(b.y);
  o[6] = (short)f2bf(b.z); o[7] = (short)f2bf(b.w);
  *(bf16x8*)d = o;
}

// ---------------- merged Wout convert: one read -> WCAT + WSEM ---------------
__global__ __launch_bounds__(256) void conv_wout_k(
    const float* __restrict__ Wout, u16* __restrict__ WCAT,
    u16* __restrict__ WSEM) {
  int t = blockIdx.x * 256 + threadIdx.x;   // 32000 * 320 jobs
  int r = t / 320, c = (t - r * 320) * 8;
  const float* s = Wout + (size_t)r * 2560 + c;
  float4 a = *(const float4*)s;
  float4 b = *(const float4*)(s + 4);
  bf16x8 o;
  o[0] = (short)f2bf(a.x); o[1] = (short)f2bf(a.y);
  o[2] = (short)f2bf(a.z); o[3] = (short)f2bf(a.w);
  o[4] = (short)f2bf(b.x); o[5] = (short)f2bf(b.y);
  o[6] = (short)f2bf(b.z); o[7] = (short)f2bf(b.w);
  u16* dst;
  if (c < 1024)      dst = WCAT + (size_t)r * 1536 + c;
  else if (c < 2048) dst = WSEM + (size_t)r * 1024 + (c - 1024);
  else               dst = WCAT + (size_t)r * 1536 + 1024 + (c - 2048);
  *(bf16x8*)dst = o;
}

// ---------------- merged small init: pack syn, pack sem, init h + flags ------
__global__ __launch_bounds__(256) void small_init_k(
    const float* __restrict__ syn, const float* __restrict__ sem,
    const float* __restrict__ hidden, u16* __restrict__ SYNB,
    u16* __restrict__ SEMB, u16* __restrict__ h0b, u16* __restrict__ h1b,
    int* __restrict__ flags) {
  int bb = blockIdx.x;
  if (bb < 128) {
    const float* src = bb < 64 ? syn : sem;
    u16* dst = bb < 64 ? SYNB : SEMB;
    int t = (bb & 63) * 256 + threadIdx.x;   // 16384 jobs
    int row = t >> 7, c = (t & 127) * 8;
    bf16x8 o = {0, 0, 0, 0, 0, 0, 0, 0};
    if (row < 16) {
      const float* s = src + row * 1024 + c;
      float4 a = *(const float4*)s;
      float4 b = *(const float4*)(s + 4);
      o[0] = (short)f2bf(a.x); o[1] = (short)f2bf(a.y);
      o[2] = (short)f2bf(a.z); o[3] = (short)f2bf(a.w);
      o[4] = (short)f2bf(b.x); o[5] = (short)f2bf(b.y);
      o[6] = (short)f2bf(b.z); o[7] = (short)f2bf(b.w);
    }
    *(bf16x8*)(dst + (size_t)row * 1024 + c) = o;
  } else {
    int i = (bb - 128) * 256 + threadIdx.x;  // 16384
    h0b[i] = f2bf(hidden[i]);
    h1b[i] = f2bf(hidden[16384 + i]);
    if (i < 4096) flags[i] = 0;
  }
}

// ---------------- embedding gather -> bf16 into XOUT[:,1024:1536] ------------
__global__ __launch_bounds__(256) void gather_emb_k(
    const int* __restrict__ seq, const float* __restrict__ table,
    u16* __restrict__ xout) {
  int t0 = blockIdx.x * 256 + threadIdx.x;
  int tb = t0 >> 6, c = (t0 & 63) * 8;
  int tt = tb >> 4, b = tb & 15;
  int tok = seq[b * 128 + tt];
  const float* s = table + (size_t)tok * 512 + c;
  float4 a = *(const float4*)s;
  float4 bb = *(const float4*)(s + 4);
  bf16x8 o;
  o[0] = (short)f2bf(a.x);  o[1] = (short)f2bf(a.y);
  o[2] = (short)f2bf(a.z);  o[3] = (short)f2bf(a.w);
  o[4] = (short)f2bf(bb.x); o[5] = (short)f2bf(bb.y);
  o[6] = (short)f2bf(bb.z); o[7] = (short)f2bf(bb.w);
  *(bf16x8*)(xout + (size_t)tb * 1536 + 1024 + c) = o;
}

// ---------------- dataflow-aligned stage: poll own producer, then load -------
// Thread tid consumes only k-slice kc = tid&127 (8 values), produced by block
// kc>>1 -> poll exactly that producer's flag inline, then coalesced load.
__device__ __forceinline__ void stage_tile_df(
    const u16* src, char* tile, int tid, const int* fl, int target) {
  if (fl) {
    const int* myf = fl + ((tid & 127) >> 1) * 16;
    while (ld_flag(myf) < target) __builtin_amdgcn_s_sleep(1);
  }
  f32x4 tmp[8];
#pragma unroll
  for (int q = 0; q < 8; ++q) {
    int c = q * 256 + tid;
    int row = c >> 7, kc = c & 127;
    tmp[q] = ld_sc_x4(src + (size_t)row * 1024 + kc * 8);
  }
  WAIT_VM0();
  __builtin_amdgcn_sched_barrier(0);
#pragma unroll
  for (int q = 0; q < 8; ++q) {
    int c = q * 256 + tid;
    int row = c >> 7, kc = c & 127;
    int byte = (row * 2048 + kc * 16) ^ ((row & 7) << 4);
    *(bf16x8*)(tile + byte) = *(bf16x8*)&tmp[q];
  }
}

// ---------------- persistent 2-layer GRU (r4 structure + dataflow polls) -----
// 192 blocks (1/CU): 0..63 L0 (16 j, Whh0 slice); 64..127 L1-ih (Wih1 slice;
// gi1 partials one stage ahead); 128..191 L1-hh (Whh1 slice, h1 + epilogue).
// Sync: spread stride-16 flags; per-thread poll of own producer (3 barriers).
__global__ __launch_bounds__(256, 1) void gru_persist3_k(
    const float* __restrict__ hidden, const u16* __restrict__ h0i,
    const u16* __restrict__ h1i, const float* __restrict__ gi0,
    const u16* __restrict__ Whh0, const u16* __restrict__ Wih1,
    const u16* __restrict__ Whh1, const float* __restrict__ bhh0,
    const float* __restrict__ bih1, const float* __restrict__ bhh1,
    u16* __restrict__ h0all, u16* __restrict__ h1all, u16* __restrict__ xout,
    float* __restrict__ part, float* __restrict__ hidf,
    float* __restrict__ last, int* __restrict__ flags) {
  extern __shared__ char ldsb[];
  char* Ab = ldsb + 98304;
  float* Cl = (float*)(ldsb + 131072);
  const int tid = threadIdx.x, bid = blockIdx.x;
  const int wave = tid >> 6, lane = tid & 63;
  const int role = bid >> 6, lb = bid & 63, jb = lb * 16;
  int* f0 = flags, *fih = flags + 1024, *f1 = flags + 2048;

  // ---- stage weight slice into LDS (once) ----
  const u16* Wsrc = role == 0 ? Whh0 : (role == 1 ? Wih1 : Whh1);
  for (int idx = tid; idx < 48 * 128; idx += 256) {
    int row = idx >> 7, c = idx & 127;
    int g = row >> 4, jj2 = row & 15;
    const u16* src = Wsrc + (size_t)(g * 1024 + jb + jj2) * 1024 + c * 8;
    int byte = (row * 2048 + c * 16) ^ ((row & 7) << 4);
    *(bf16x8*)(ldsb + byte) = *(const bf16x8*)src;
  }

  // ---- per-thread epilogue identity: b = tid>>4, jj = tid&15 ----
  const int eb = tid >> 4, jj = tid & 15, j = jb + jj;
  float hp = 0.f, bR = 0.f, bZ = 0.f, bN = 0.f, iR = 0.f, iZ = 0.f, iN = 0.f;
  if (role == 0) {
    hp = hidden[eb * 1024 + j];
    bR = bhh0[j]; bZ = bhh0[1024 + j]; bN = bhh0[2048 + j];
  } else if (role == 2) {
    hp = hidden[16384 + eb * 1024 + j];
    bR = bhh1[j]; bZ = bhh1[1024 + j]; bN = bhh1[2048 + j];
    iR = bih1[j]; iZ = bih1[1024 + j]; iN = bih1[2048 + j];
  }
  __syncthreads();

  const int arow = lane & 15, aq = lane >> 4;
  for (int t = 0; t < 128; ++t) {
    // ---- 1. stage A tile: per-thread producer poll + coalesced load ----
    const u16* asrc;
    const int* fl;
    int target;
    if (role == 0) {
      asrc = t ? h0all + (size_t)(t - 1) * 16384 : h0i;
      fl = t ? f0 : nullptr; target = t;
    } else if (role == 1) {
      asrc = h0all + (size_t)t * 16384;
      fl = f0; target = t + 1;
    } else {
      asrc = t ? h1all + (size_t)(t - 1) * 16384 : h1i;
      fl = t ? f1 : nullptr; target = t;
    }
    stage_tile_df(asrc, Ab, tid, fl, target);
    __syncthreads();                              // S1: A tile complete

    // ---- 2. MFMA: 3 gate chains (ILP), A+B from LDS; wave w does ks=w+4i ----
    {
      f32x4 a0 = {0.f, 0.f, 0.f, 0.f}, a1 = a0, a2 = a0;
#pragma unroll
      for (int i = 0; i < 8; ++i) {
        int ks = wave + i * 4;
        int abyte = (arow * 2048 + ks * 64 + aq * 16) ^ ((arow & 7) << 4);
        bf16x8 af = *(const bf16x8*)(Ab + abyte);
        int r0 = arow, r1 = 16 + arow, r2 = 32 + arow;
        bf16x8 b0 = *(const bf16x8*)(
            ldsb + ((r0 * 2048 + ks * 64 + aq * 16) ^ ((r0 & 7) << 4)));
        bf16x8 b1 = *(const bf16x8*)(
            ldsb + ((r1 * 2048 + ks * 64 + aq * 16) ^ ((r1 & 7) << 4)));
        bf16x8 b2 = *(const bf16x8*)(
            ldsb + ((r2 * 2048 + ks * 64 + aq * 16) ^ ((r2 & 7) << 4)));
        a0 = __builtin_amdgcn_mfma_f32_16x16x32_bf16(af, b0, a0, 0, 0, 0);
        a1 = __builtin_amdgcn_mfma_f32_16x16x32_bf16(af, b1, a1, 0, 0, 0);
        a2 = __builtin_amdgcn_mfma_f32_16x16x32_bf16(af, b2, a2, 0, 0, 0);
      }
#pragma unroll
      for (int r = 0; r < 4; ++r) {
        int ci = (aq * 4 + r) * 16 + arow + aq * 8;  // conflict-break offset
        Cl[(0 * 4 + wave) * 288 + ci] = a0[r];
        Cl[(1 * 4 + wave) * 288 + ci] = a1[r];
        Cl[(2 * 4 + wave) * 288 + ci] = a2[r];
      }
    }
    // hh: wait for this stage's gi1 partial flag while C settles
    if (role == 2 && tid == 0)
      while (ld_flag(fih + lb * 16) < t + 1) __builtin_amdgcn_s_sleep(1);
    __syncthreads();                              // S2: C tile + fih visible

    // ---- 3. epilogue ----
    {
      int ci = eb * 16 + jj + (eb >> 2) * 8;
      float s0 = Cl[0 * 288 + ci] + Cl[1 * 288 + ci] +
                 Cl[2 * 288 + ci] + Cl[3 * 288 + ci];
      float s1 = Cl[4 * 288 + ci] + Cl[5 * 288 + ci] +
                 Cl[6 * 288 + ci] + Cl[7 * 288 + ci];
      float s2 = Cl[8 * 288 + ci] + Cl[9 * 288 + ci] +
                 Cl[10 * 288 + ci] + Cl[11 * 288 + ci];
      if (role == 1) {
        float* pp = part + ((size_t)t * 64 + lb) * 768 + eb * 16 + jj;
        st_sc_f32(pp, s0);
        st_sc_f32(pp + 256, s1);
        st_sc_f32(pp + 512, s2);
        WAIT_VM0();
      } else {
        float ir, iz, inn;
        if (role == 0) {
          const float* g = gi0 + ((size_t)t * 16 + eb) * 3072 + j;
          ir = g[0]; iz = g[1024]; inn = g[2048];
        } else {
          const float* pp = part + ((size_t)t * 64 + lb) * 768 + eb * 16 + jj;
          float p0 = ld_sc_f32(pp), p1 = ld_sc_f32(pp + 256),
                p2 = ld_sc_f32(pp + 512);
          WAIT_VM0();
          __builtin_amdgcn_sched_barrier(0);  // rule #18: pin VALU below wait
          ir = p0 + iR; iz = p1 + iZ; inn = p2 + iN;
        }
        float r = 1.f / (1.f + __expf(-(ir + s0 + bR)));
        float z = 1.f / (1.f + __expf(-(iz + s1 + bZ)));
        float n = tanhf(inn + r * (s2 + bN));
        float hnew = (1.f - z) * n + z * hp;
        hp = hnew;
        u16 hb = f2bf(hnew);
        if (role == 0) {
          st_sc_u16(h0all + ((size_t)t * 16 + eb) * 1024 + j, (unsigned)hb);
          if (t == 127) hidf[eb * 1024 + j] = hnew;
        } else {
          st_sc_u16(h1all + ((size_t)t * 16 + eb) * 1024 + j, (unsigned)hb);
          xout[((size_t)t * 16 + eb) * 1536 + j] = hb;  // plain store
          if (t == 127) {
            hidf[16384 + eb * 1024 + j] = hnew;
            last[eb * 1024 + j] = hnew;
          }
        }
        WAIT_VM0();
      }
    }
    __syncthreads();                              // S3: all stores acked
    // ---- 4. publish flag ----
    if (tid == 0) {
      if (role == 0)      st_flag(f0 + lb * 16, t + 1);
      else if (role == 1) st_flag(fih + lb * 16, t + 1);
      else                st_flag(f1 + lb * 16, t + 1);
    }
  }
}

// ---------------- bf16 MFMA GEMM (BM=128, 3-buffer counted-vmcnt) ------------
template <int MODE>
__global__ __launch_bounds__(256) void gemm_bt_k(
    const u16* __restrict__ A, int lda, const u16* __restrict__ Bw, int ldb,
    float* __restrict__ C, int ldc, const float* __restrict__ add,
    int N, int K) {
  __shared__ u16 Asm_[3][128 * 32];
  __shared__ u16 Bsm_[3][128 * 32];
  const int m0 = blockIdx.x * 128, n0 = blockIdx.y * 128;
  const int tid = threadIdx.x, wave = tid >> 6, lane = tid & 63;
  const int wm = (wave >> 1) * 64, wn = (wave & 1) * 64;
  const int lrow = lane & 15, lk = (lane >> 4) * 8;

  auto STAGE = [&](int buf, int k0) {
#pragma unroll
    for (int q = 0; q < 2; ++q) {
      int c = (wave * 2 + q) * 64 + lane;
      int row = c >> 2, seg = c & 3;
      const u16* src = A + (size_t)(m0 + row) * lda + k0 + seg * 8;
      u16* dst = Asm_[buf] + (wave * 2 + q) * 512;
      __builtin_amdgcn_global_load_lds(
          (const __attribute__((address_space(1))) void*)src,
          (__attribute__((address_space(3))) void*)dst, 16, 0, 0);
    }
#pragma unroll
    for (int q = 0; q < 2; ++q) {
      int c = (wave * 2 + q) * 64 + lane;
      int row = c >> 2, seg = c & 3;
      const u16* src = Bw + (size_t)(n0 + row) * ldb + k0 + seg * 8;
      u16* dst = Bsm_[buf] + (wave * 2 + q) * 512;
      __builtin_amdgcn_global_load_lds(
          (const __attribute__((address_space(1))) void*)src,
          (__attribute__((address_space(3))) void*)dst, 16, 0, 0);
    }
  };

  const int nIt = K >> 5;
  STAGE(0, 0);
  if (1 < nIt) STAGE(1, 32);
  f32x4 acc[4][4] = {};
  for (int it = 0; it < nIt; ++it) {
    const int cur = it % 3;
    if (it + 1 < nIt) { asm volatile("s_waitcnt vmcnt(4)" ::: "memory"); }
    else              { asm volatile("s_waitcnt vmcnt(0)" ::: "memory"); }
    __syncthreads();
    if (it + 2 < nIt) STAGE((it + 2) % 3, (it + 2) * 32);
    bf16x8 af[4], bfr[4];
#pragma unroll
    for (int i = 0; i < 4; ++i) {
      af[i]  = *(const bf16x8*)(Asm_[cur] + (wm + i * 16 + lrow) * 32 + lk);
      bfr[i] = *(const bf16x8*)(Bsm_[cur] + (wn + i * 16 + lrow) * 32 + lk);
    }
#pragma unroll
    for (int i = 0; i < 4; ++i)
#pragma unroll
      for (int jx = 0; jx < 4; ++jx)
        acc[i][jx] = __builtin_amdgcn_mfma_f32_16x16x32_bf16(
            af[i], bfr[jx], acc[i][jx], 0, 0, 0);
  }
  const int lr4 = (lane >> 4) * 4;
#pragma unroll
  for (int i = 0; i < 4; ++i) {
#pragma unroll
    for (int jx = 0; jx < 4; ++jx) {
      int gc = n0 + wn + jx * 16 + lrow;
#pragma unroll
      for (int r = 0; r < 4; ++r) {
        int gr = m0 + wm + i * 16 + lr4 + r;
        float v = acc[i][jx][r];
        if (MODE == 1) v += add[(gr & 15) * N + gc];
        else if (MODE == 2) v += add[gc];
        C[(size_t)gr * ldc + gc] = v;
      }
    }
  }
}

// ---------------- bf16 MFMA GEMM (BM=256, BN=128, 512 thr, 3-buffer) ---------
// LDS 72 KB dynamic, 2 blocks/CU. (Measured best for the big GEMMs.)
template <int MODE, bool SWZ>
__global__ __launch_bounds__(512) void gemm256_bt_k(
    const u16* __restrict__ A, int lda, const u16* __restrict__ Bw, int ldb,
    float* __restrict__ C, int ldc, const float* __restrict__ add,
    int N, int K) {
  extern __shared__ u16 lds256[];
  u16* Asm_ = lds256;              // 3 x 8192 u16 (16 KB each)
  u16* Bsm_ = lds256 + 3 * 8192;   // 3 x 4096 u16 (8 KB each)
  int bx = blockIdx.x, by = blockIdx.y;
  if (SWZ) {
    int nx = gridDim.x;
    int orig = by * nx + bx;
    int cpx = (nx * gridDim.y) >> 3;
    int wg = (orig & 7) * cpx + (orig >> 3);
    bx = wg % nx; by = wg / nx;
  }
  const int m0 = bx * 256, n0 = by * 128;
  const int tid = threadIdx.x, wave = tid >> 6, lane = tid & 63;
  const int wm = (wave >> 1) * 64, wn = (wave & 1) * 64;
  const int lrow = lane & 15, lk = (lane >> 4) * 8;

  auto STAGE = [&](int buf, int k0) {
#pragma unroll
    for (int q = 0; q < 2; ++q) {                    // A: 256x32 = 16KB
      int c = (q * 8 + wave) * 64 + lane;
      int row = c >> 2, seg = c & 3;
      const u16* src = A + (size_t)(m0 + row) * lda + k0 + seg * 8;
      u16* dst = Asm_ + buf * 8192 + (q * 8 + wave) * 512;
      __builtin_amdgcn_global_load_lds(
          (const __attribute__((address_space(1))) void*)src,
          (__attribute__((address_space(3))) void*)dst, 16, 0, 0);
    }
    {                                                // B: 128x32 = 8KB
      int c = wave * 64 + lane;
      int row = c >> 2, seg = c & 3;
      const u16* src = Bw + (size_t)(n0 + row) * ldb + k0 + seg * 8;
      u16* dst = Bsm_ + buf * 4096 + wave * 512;
      __builtin_amdgcn_global_load_lds(
          (const __attribute__((address_space(1))) void*)src,
          (__attribute__((address_space(3))) void*)dst, 16, 0, 0);
    }
  };

  const int nIt = K >> 5;
  STAGE(0, 0);
  if (1 < nIt) STAGE(1, 32);
  f32x4 acc[4][4] = {};
  for (int it = 0; it < nIt; ++it) {
    const int cur = it % 3;
    if (it + 1 < nIt) { asm volatile("s_waitcnt vmcnt(3)" ::: "memory"); }
    else              { asm volatile("s_waitcnt vmcnt(0)" ::: "memory"); }
    __syncthreads();
    if (it + 2 < nIt) STAGE((it + 2) % 3, (it + 2) * 32);
    bf16x8 af[4], bfr[4];
#pragma unroll
    for (int i = 0; i < 4; ++i) {
      af[i]  = *(const bf16x8*)(Asm_ + cur * 8192 + (wm + i * 16 + lrow) * 32 + lk);
      bfr[i] = *(const bf16x8*)(Bsm_ + cur * 4096 + (wn + i * 16 + lrow) * 32 + lk);
    }
#pragma unroll
    for (int i = 0; i < 4; ++i)
#pragma unroll
      for (int jx = 0; jx < 4; ++jx)
        acc[i][jx] = __builtin_amdgcn_mfma_f32_16x16x32_bf16(
            af[i], bfr[jx], acc[i][jx], 0, 0, 0);
  }
  const int lr4 = (lane >> 4) * 4;
#pragma unroll
  for (int i = 0; i < 4; ++i) {
#pragma unroll
    for (int jx = 0; jx < 4; ++jx) {
      int gc = n0 + wn + jx * 16 + lrow;
#pragma unroll
      for (int r = 0; r < 4; ++r) {
        int gr = m0 + wm + i * 16 + lr4 + r;
        float v = acc[i][jx][r];
        if (MODE == 1) v += add[(gr & 15) * N + gc];
        else if (MODE == 2) v += add[gc];
        C[(size_t)gr * ldc + gc] = v;
      }
    }
  }
}

// ---------------- row-wise log_softmax, online (m,s) single read pass --------
__global__ __launch_bounds__(256) void log_softmax_k(
    const float* __restrict__ logits, float* __restrict__ scores) {
  int row = blockIdx.x;
  const float* x = logits + (size_t)row * 32000;
  float* y = scores + (size_t)row * 32000;
  __shared__ float redm[4], reds[4];
  int tid = threadIdx.x;
  float m = -3.4e38f, s = 0.f;
  for (int idx = tid * 4; idx < 32000; idx += 1024) {
    float4 v = *(const float4*)(x + idx);
    float cm = fmaxf(fmaxf(v.x, v.y), fmaxf(v.z, v.w));
    if (cm > m) { s *= __expf(m - cm); m = cm; }
    s += __expf(v.x - m) + __expf(v.y - m) + __expf(v.z - m) + __expf(v.w - m);
  }
  for (int off = 1; off < 64; off <<= 1) {
    float mo = __shfl_xor(m, off), so = __shfl_xor(s, off);
    float nm = fmaxf(m, mo);
    s = s * __expf(m - nm) + so * __expf(mo - nm);
    m = nm;
  }
  if ((tid & 63) == 0) { redm[tid >> 6] = m; reds[tid >> 6] = s; }
  __syncthreads();
  {
    float fm = fmaxf(fmaxf(redm[0], redm[1]), fmaxf(redm[2], redm[3]));
    float fs = reds[0] * __expf(redm[0] - fm) + reds[1] * __expf(redm[1] - fm) +
               reds[2] * __expf(redm[2] - fm) + reds[3] * __expf(redm[3] - fm);
    float lse = fm + logf(fs);
    for (int idx = tid * 4; idx < 32000; idx += 1024) {
      float4 v = *(const float4*)(x + idx);
      float4 o;
      o.x = v.x - lse; o.y = v.y - lse; o.z = v.z - lse; o.w = v.w - lse;
      *(float4*)(y + idx) = o;
    }
  }
}

// =============================================================================
extern "C" void kernel_launch(void* const* d_in, const int* in_sizes, int n_in,
                              void* d_out, int out_size, void* d_ws,
                              size_t ws_size, hipStream_t stream) {
  const int*   seq    = (const int*)d_in[0];
  const float* sem    = (const float*)d_in[2];
  const float* syn    = (const float*)d_in[3];
  const float* hidden = (const float*)d_in[4];
  const float* table  = (const float*)d_in[5];
  const float* Wih0   = (const float*)d_in[6];
  const float* Whh0   = (const float*)d_in[7];
  const float* bih0   = (const float*)d_in[8];
  const float* bhh0   = (const float*)d_in[9];
  const float* Wih1   = (const float*)d_in[10];
  const float* Whh1   = (const float*)d_in[11];
  const float* bih1   = (const float*)d_in[12];
  const float* bhh1   = (const float*)d_in[13];
  const float* Wout   = (const float*)d_in[14];
  const float* bout   = (const float*)d_in[15];

  char* base = (char*)d_out;
  float* scores = (float*)base;
  u16*   WCAT   = (u16*)(base + OFF_WCAT);
  u16*   WSEM   = (u16*)(base + OFF_WSEM);
  float* PART   = (float*)(base + OFF_PART);
  u16*   H1ALL  = (u16*)(base + OFF_H1ALL);
  float* GI0    = (float*)(base + OFF_GI0);
  u16*   XOUT   = (u16*)(base + OFF_XOUT);
  u16*   H0ALL  = (u16*)(base + OFF_H0ALL);
  u16*   WIH0E  = (u16*)(base + OFF_WIH0E);
  u16*   WIH0S  = (u16*)(base + OFF_WIH0S);
  u16*   WHH0B  = (u16*)(base + OFF_WHH0);
  u16*   WIH1B  = (u16*)(base + OFF_WIH1);
  u16*   WHH1B  = (u16*)(base + OFF_WHH1);
  u16*   SYNB   = (u16*)(base + OFF_SYNB);
  u16*   SEMB   = (u16*)(base + OFF_SEMB);
  float* BASE0  = (float*)(base + OFF_BASE0);
  float* BASEO  = (float*)(base + OFF_BASEO);
  u16*   H0IBF  = (u16*)(base + OFF_H0IBF);
  u16*   H1IBF  = (u16*)(base + OFF_H1IBF);
  int*   FLAGS  = (int*)(base + OFF_FLAGS);
  float* hidf   = (float*)(base + OFF_HIDF);
  float* last   = (float*)(base + OFF_LAST);
  float* logits = (float*)(base + OFF_LOGIT);

  // weight conversions to bf16 (merged: Wout one pass; recurrence one kernel)
  conv_wout_k<<<40000, 256, 0, stream>>>(Wout, WCAT, WSEM);
  conv_recw_k<<<6912, 256, 0, stream>>>(
      Wih0, Whh0, Wih1, Whh1, WIH0E, WIH0S, WHH0B, WIH1B, WHH1B);

  // embeddings + packed small operands + init (merged)
  gather_emb_k<<<512, 256, 0, stream>>>(seq, table, XOUT);
  small_init_k<<<192, 256, 0, stream>>>(
      syn, sem, hidden, SYNB, SEMB, H0IBF, H1IBF, FLAGS);

  // time-invariant bases via MFMA GEMM (M padded to 128; rows 16..127 junk)
  gemm_bt_k<2><<<dim3(1, 24), 256, 0, stream>>>(
      SYNB, 1024, WIH0S, 1024, BASE0, 3072, bih0, 3072, 1024);
  gemm_bt_k<2><<<dim3(1, 250), 256, 0, stream>>>(
      SEMB, 1024, WSEM, 1024, BASEO, 32000, bout, 32000, 1024);

  // gi0 for all t: embs @ Wih0e.T + base0 (BM=256xBN=128, grid 192 = 8*24)
  hipFuncSetAttribute((const void*)(gemm256_bt_k<1, true>),
                      hipFuncAttributeMaxDynamicSharedMemorySize, 73728);
  gemm256_bt_k<1, true><<<dim3(8, 24), 512, 73728, stream>>>(
      XOUT + 1024, 1536, WIH0E, 512, GI0, 3072, BASE0, 3072, 512);

  // persistent recurrence (r4 structure + dataflow-aligned polls)
  hipFuncSetAttribute((const void*)gru_persist3_k,
                      hipFuncAttributeMaxDynamicSharedMemorySize, 145408);
  gru_persist3_k<<<192, 256, 145408, stream>>>(
      hidden, H0IBF, H1IBF, GI0, WHH0B, WIH1B, WHH1B, bhh0, bih1, bhh1,
      H0ALL, H1ALL, XOUT, PART, hidf, last, FLAGS);

  // logits = [h1 | emb] @ WCAT.T + baseo (BM=256xBN=128, grid 2000 = 8*250)
  gemm256_bt_k<1, true><<<dim3(8, 250), 512, 73728, stream>>>(
      XOUT, 1536, WCAT, 1536, logits, 32000, BASEO, 32000, 1536);

  // scores = log_softmax(logits) — the only writer of the scores region
  log_softmax_k<<<2048, 256, 0, stream>>>(logits, scores);
}